// Round 1
// baseline (1257.711 us; speedup 1.0000x reference)
//
#include <hip/hip_runtime.h>
#include <hip/hip_bf16.h>

// CGCNN forward, f32 compute, bf16 storage for the pre-BN activation t.
// Decomposition: t[n,m,:] = hi_proj[n,:] + hj_proj[idx[n,m],:] + bond[n,m,:]@w_b (+bias in hi_proj)
// BN over full batch -> two-phase per layer with deterministic block partials.

#define NN 40000
#define MM 12
#define AA 64
#define LL 3
#define CC 128
#define F0C 92
#define NBOND (NN*MM)
#define EPSBN 1e-5f

#define G_BOND 1500
#define G_APPLY 1250

__device__ __forceinline__ float softplusf_(float x) {
    return fmaxf(x, 0.f) + log1pf(expf(-fabsf(x)));
}
__device__ __forceinline__ float sigmoidf_(float x) {
    return 1.f / (1.f + expf(-x));
}
__device__ __forceinline__ unsigned short f2bf(float f) {
    unsigned int u = __float_as_uint(f);
    unsigned int r = (u + 0x7fffu + ((u >> 16) & 1u)) >> 16;
    return (unsigned short)r;
}
__device__ __forceinline__ float bf2f(unsigned short s) {
    return __uint_as_float(((unsigned int)s) << 16);
}

// ---------------- fc1: h = site @ fc1_w + fc1_b  (40000x92 @ 92x64) ----------------
__global__ __launch_bounds__(256) void k_fc1(const float* __restrict__ site,
        const float* __restrict__ w, const float* __restrict__ b,
        float* __restrict__ h) {
    __shared__ float w_s[F0C][AA];
    __shared__ float x_s[16][F0C];
    int tid = threadIdx.x;
    for (int i = tid; i < F0C * AA; i += 256) w_s[i / AA][i % AA] = w[i];
    int n0 = blockIdx.x * 16;
    for (int i = tid; i < 16 * F0C; i += 256) x_s[i / F0C][i % F0C] = site[(size_t)n0 * F0C + i];
    __syncthreads();
    int d = tid & 63, ng = tid >> 6;
    float bb = b[d];
    float acc[4] = {bb, bb, bb, bb};
    #pragma unroll 4
    for (int k = 0; k < F0C; ++k) {
        float wv = w_s[k][d];
        acc[0] += x_s[ng][k] * wv;
        acc[1] += x_s[ng + 4][k] * wv;
        acc[2] += x_s[ng + 8][k] * wv;
        acc[3] += x_s[ng + 12][k] * wv;
    }
    #pragma unroll
    for (int rr = 0; rr < 4; ++rr)
        h[(size_t)(n0 + ng + rr * 4) * AA + d] = acc[rr];
}

// ---------------- proj: hi = h@w_i + bias, hj = h@w_j  (40000x64 @ 64x128 x2) ----------------
__global__ __launch_bounds__(256) void k_proj(const float* __restrict__ h,
        const float* __restrict__ convw, const float* __restrict__ convb,
        float* __restrict__ hi, float* __restrict__ hj) {
    __shared__ float w_s[64][256];   // cols 0..127 = w_i, 128..255 = w_j
    __shared__ float hT[64][36];     // transposed h tile [k][row]
    int tid = threadIdx.x;
    for (int i = tid; i < 64 * 256; i += 256) {
        int k = i >> 8, c = i & 255;
        w_s[k][c] = convw[(size_t)((c < 128 ? k : 64 + k)) * 128 + (c & 127)];
    }
    int row0 = blockIdx.x * 32;
    for (int i = tid; i < 2048; i += 256) {
        int r = i >> 6, k = i & 63;
        hT[k][r] = h[(size_t)(row0 + r) * 64 + k];
    }
    __syncthreads();
    int c0 = (tid & 63) * 4;
    int r0 = (tid >> 6) * 8;
    float acc[8][4];
    #pragma unroll
    for (int r = 0; r < 8; ++r)
        #pragma unroll
        for (int i = 0; i < 4; ++i) acc[r][i] = 0.f;
    #pragma unroll 4
    for (int k = 0; k < 64; ++k) {
        float4 w4 = *(const float4*)&w_s[k][c0];
        float4 ha = *(const float4*)&hT[k][r0];
        float4 hb = *(const float4*)&hT[k][r0 + 4];
        float wv[4] = {w4.x, w4.y, w4.z, w4.w};
        float hv[8] = {ha.x, ha.y, ha.z, ha.w, hb.x, hb.y, hb.z, hb.w};
        #pragma unroll
        for (int r = 0; r < 8; ++r)
            #pragma unroll
            for (int i = 0; i < 4; ++i) acc[r][i] += hv[r] * wv[i];
    }
    bool isHi = (c0 < 128);
    int cc = isHi ? c0 : c0 - 128;
    float4 cb4 = make_float4(0.f, 0.f, 0.f, 0.f);
    if (isHi) cb4 = *(const float4*)&convb[c0];
    float* dst = isHi ? hi : hj;
    #pragma unroll
    for (int r = 0; r < 8; ++r) {
        int n = row0 + r0 + r;
        float4 o = make_float4(acc[r][0] + cb4.x, acc[r][1] + cb4.y,
                               acc[r][2] + cb4.z, acc[r][3] + cb4.w);
        *(float4*)&dst[(size_t)n * 128 + cc] = o;
    }
}

// ---------------- bond GEMM + t assembly + bn1 partial stats ----------------
__global__ __launch_bounds__(256) void k_bond(const float* __restrict__ bf,
        const float* __restrict__ wb,
        const float* __restrict__ hi, const float* __restrict__ hj,
        const int* __restrict__ bidx,
        unsigned short* __restrict__ tbuf,
        float* __restrict__ part1) {
    __shared__ float w_s[64][128];
    __shared__ float bT[64][36];
    __shared__ float red[8][132];
    int tid = threadIdx.x;
    for (int i = tid; i < 8192; i += 256) w_s[i >> 7][i & 127] = wb[i];
    int cg = tid & 31, bg = tid >> 5;
    int c0 = cg * 4, b0 = bg * 4;
    float sum[4] = {0, 0, 0, 0}, sq[4] = {0, 0, 0, 0};
    for (int tile = blockIdx.x; tile < NBOND / 32; tile += G_BOND) {
        int bond0 = tile * 32;
        __syncthreads();
        for (int i = tid; i < 2048; i += 256) {
            int r = i >> 6, k = i & 63;
            bT[k][r] = bf[(size_t)(bond0 + r) * 64 + k];
        }
        __syncthreads();
        float acc[4][4];
        #pragma unroll
        for (int b = 0; b < 4; ++b)
            #pragma unroll
            for (int i = 0; i < 4; ++i) acc[b][i] = 0.f;
        #pragma unroll 4
        for (int k = 0; k < 64; ++k) {
            float4 w4 = *(const float4*)&w_s[k][c0];
            float4 b4 = *(const float4*)&bT[k][b0];
            float wv[4] = {w4.x, w4.y, w4.z, w4.w};
            float bv[4] = {b4.x, b4.y, b4.z, b4.w};
            #pragma unroll
            for (int b = 0; b < 4; ++b)
                #pragma unroll
                for (int i = 0; i < 4; ++i) acc[b][i] += bv[b] * wv[i];
        }
        #pragma unroll
        for (int b = 0; b < 4; ++b) {
            int bond = bond0 + b0 + b;
            int n = bond / MM;
            int j = bidx[bond];
            float4 hi4 = *(const float4*)&hi[(size_t)n * 128 + c0];
            float4 hj4 = *(const float4*)&hj[(size_t)j * 128 + c0];
            float t0 = acc[b][0] + hi4.x + hj4.x;
            float t1 = acc[b][1] + hi4.y + hj4.y;
            float t2 = acc[b][2] + hi4.z + hj4.z;
            float t3 = acc[b][3] + hi4.w + hj4.w;
            sum[0] += t0; sq[0] += t0 * t0;
            sum[1] += t1; sq[1] += t1 * t1;
            sum[2] += t2; sq[2] += t2 * t2;
            sum[3] += t3; sq[3] += t3 * t3;
            ushort4 u;
            u.x = f2bf(t0); u.y = f2bf(t1); u.z = f2bf(t2); u.w = f2bf(t3);
            *(ushort4*)&tbuf[(size_t)bond * 128 + c0] = u;
        }
    }
    __syncthreads();
    #pragma unroll
    for (int i = 0; i < 4; ++i) red[bg][c0 + i] = sum[i];
    __syncthreads();
    if (tid < 128) {
        float s = 0;
        #pragma unroll
        for (int g = 0; g < 8; ++g) s += red[g][tid];
        part1[(size_t)blockIdx.x * 256 + tid] = s;
    }
    __syncthreads();
    #pragma unroll
    for (int i = 0; i < 4; ++i) red[bg][c0 + i] = sq[i];
    __syncthreads();
    if (tid < 128) {
        float s = 0;
        #pragma unroll
        for (int g = 0; g < 8; ++g) s += red[g][tid];
        part1[(size_t)blockIdx.x * 256 + 128 + tid] = s;
    }
}

// ---------------- finalize bn1 -> scale/shift ----------------
__global__ void k_fin1(const float* __restrict__ part1, const float* __restrict__ g,
                       const float* __restrict__ b, float* __restrict__ scsh) {
    int c = threadIdx.x;  // 128
    float s = 0, q = 0;
    for (int r = 0; r < G_BOND; ++r) {
        s += part1[(size_t)r * 256 + c];
        q += part1[(size_t)r * 256 + 128 + c];
    }
    float m = s / (float)NBOND;
    float v = q / (float)NBOND - m * m;
    float sc = g[c] * rsqrtf(v + EPSBN);
    scsh[c] = sc;
    scsh[128 + c] = b[c] - m * sc;
}

// ---------------- apply bn1 + gated sum over m + bn2 partial stats ----------------
__global__ __launch_bounds__(256) void k_apply(const unsigned short* __restrict__ tbuf,
        const float* __restrict__ scsh, float* __restrict__ s_out,
        float* __restrict__ part2) {
    __shared__ float red[4][68];
    int tid = threadIdx.x;
    int c = tid & 63, ng = tid >> 6;
    float scf = scsh[c], shf = scsh[128 + c];
    float scc = scsh[64 + c], shc = scsh[192 + c];
    float sum = 0, sq = 0;
    for (int q = blockIdx.x; q < NN / 4; q += G_APPLY) {
        int n = q * 4 + ng;
        const unsigned short* tb = tbuf + (size_t)n * MM * 128;
        float sacc = 0.f;
        #pragma unroll
        for (int m = 0; m < MM; ++m) {
            float tf = bf2f(tb[m * 128 + c]);
            float tc = bf2f(tb[m * 128 + 64 + c]);
            sacc += sigmoidf_(scf * tf + shf) * softplusf_(scc * tc + shc);
        }
        s_out[(size_t)n * 64 + c] = sacc;
        sum += sacc; sq += sacc * sacc;
    }
    red[ng][c] = sum;
    __syncthreads();
    if (tid < 64) {
        float t = red[0][tid] + red[1][tid] + red[2][tid] + red[3][tid];
        part2[(size_t)blockIdx.x * 128 + tid] = t;
    }
    __syncthreads();
    red[ng][c] = sq;
    __syncthreads();
    if (tid < 64) {
        float t = red[0][tid] + red[1][tid] + red[2][tid] + red[3][tid];
        part2[(size_t)blockIdx.x * 128 + 64 + tid] = t;
    }
}

// ---------------- finalize bn2 ----------------
__global__ void k_fin2(const float* __restrict__ part2, const float* __restrict__ g,
                       const float* __restrict__ b, float* __restrict__ scsh2) {
    int c = threadIdx.x;  // 64
    float s = 0, q = 0;
    for (int r = 0; r < G_APPLY; ++r) {
        s += part2[(size_t)r * 128 + c];
        q += part2[(size_t)r * 128 + 64 + c];
    }
    float m = s / (float)NN;
    float v = q / (float)NN - m * m;
    float sc = g[c] * rsqrtf(v + EPSBN);
    scsh2[c] = sc;
    scsh2[64 + c] = b[c] - m * sc;
}

// ---------------- h = softplus(h + bn2(s)) ----------------
__global__ __launch_bounds__(256) void k_upd(float* __restrict__ h, const float* __restrict__ s,
        const float* __restrict__ scsh2) {
    size_t i = ((size_t)blockIdx.x * 256 + threadIdx.x) * 4;
    int c0 = (int)(i & 63);
    float4 hv = *(const float4*)&h[i];
    float4 sv = *(const float4*)&s[i];
    float4 o;
    o.x = softplusf_(hv.x + scsh2[c0 + 0] * sv.x + scsh2[64 + c0 + 0]);
    o.y = softplusf_(hv.y + scsh2[c0 + 1] * sv.y + scsh2[64 + c0 + 1]);
    o.z = softplusf_(hv.z + scsh2[c0 + 2] * sv.z + scsh2[64 + c0 + 2]);
    o.w = softplusf_(hv.w + scsh2[c0 + 3] * sv.w + scsh2[64 + c0 + 3]);
    *(float4*)&h[i] = o;
}

// ---------------- pooling: segment mean (crystal_idx sorted) ----------------
__device__ __forceinline__ int lbound(const int* a, int n, int v) {
    int lo = 0, hi = n;
    while (lo < hi) { int mid = (lo + hi) >> 1; if (a[mid] < v) lo = mid + 1; else hi = mid; }
    return lo;
}

__global__ __launch_bounds__(256) void k_pool(const float* __restrict__ h,
        const int* __restrict__ cidx, float* __restrict__ feats) {
    __shared__ float red[4][68];
    __shared__ int bounds[2];
    int c = blockIdx.x, tid = threadIdx.x;
    if (tid == 0) {
        bounds[0] = lbound(cidx, NN, c);
        bounds[1] = lbound(cidx, NN, c + 1);
    }
    __syncthreads();
    int lo = bounds[0], hi = bounds[1];
    int d = tid & 63, g = tid >> 6;
    float acc = 0;
    for (int n = lo + g; n < hi; n += 4) acc += h[(size_t)n * 64 + d];
    red[g][d] = acc;
    __syncthreads();
    if (tid < 64) {
        float t = red[0][tid] + red[1][tid] + red[2][tid] + red[3][tid];
        int cnt = hi - lo;
        feats[(size_t)c * 65 + tid] = t / (float)(cnt > 0 ? cnt : 1);
    }
}

// ---------------- head part 1: fill col 64, top BN + softplus ----------------
__global__ __launch_bounds__(128) void k_head1(float* __restrict__ feats, const float* __restrict__ fap,
        const float* __restrict__ g, const float* __restrict__ b, float* __restrict__ featsp) {
    int tid = threadIdx.x;
    if (tid < CC) feats[(size_t)tid * 65 + 64] = fap[tid];
    __syncthreads();
    if (tid < 65) {
        float s = 0;
        for (int r = 0; r < CC; ++r) s += feats[r * 65 + tid];
        float m = s / (float)CC;
        float v = 0;
        for (int r = 0; r < CC; ++r) { float d = feats[r * 65 + tid] - m; v += d * d; }
        v /= (float)CC;
        float sc = g[tid] * rsqrtf(v + EPSBN);
        float sh = b[tid] - m * sc;
        for (int r = 0; r < CC; ++r)
            featsp[r * 65 + tid] = softplusf_(sc * feats[r * 65 + tid] + sh);
    }
}

// ---------------- head part 2: fc2 + softplus + fc3 ----------------
__global__ __launch_bounds__(128) void k_head2(const float* __restrict__ featsp,
        const float* __restrict__ fc2w, const float* __restrict__ fc2b,
        const float* __restrict__ fc3w, const float* __restrict__ fc3b,
        float* __restrict__ out) {
    __shared__ float fr[65];
    __shared__ float red[128];
    int r = blockIdx.x, tid = threadIdx.x;
    if (tid < 65) fr[tid] = featsp[(size_t)r * 65 + tid];
    __syncthreads();
    float acc = fc2b[tid];
    for (int k = 0; k < 65; ++k) acc += fr[k] * fc2w[k * 128 + tid];
    red[tid] = softplusf_(acc) * fc3w[tid];
    __syncthreads();
    for (int st = 64; st > 0; st >>= 1) {
        if (tid < st) red[tid] += red[tid + st];
        __syncthreads();
    }
    if (tid == 0) out[r] = red[0] + fc3b[0];
}

extern "C" void kernel_launch(void* const* d_in, const int* in_sizes, int n_in,
                              void* d_out, int out_size, void* d_ws, size_t ws_size,
                              hipStream_t stream) {
    const float* site  = (const float*)d_in[0];
    const float* bondf = (const float*)d_in[1];
    const float* fap   = (const float*)d_in[2];
    const float* fc1w  = (const float*)d_in[3];
    const float* fc1b  = (const float*)d_in[4];
    const float* convw = (const float*)d_in[5];
    const float* convb = (const float*)d_in[6];
    const float* bn1g  = (const float*)d_in[7];
    const float* bn1b  = (const float*)d_in[8];
    const float* bn2g  = (const float*)d_in[9];
    const float* bn2b  = (const float*)d_in[10];
    const float* topg  = (const float*)d_in[11];
    const float* topb  = (const float*)d_in[12];
    const float* fc2w  = (const float*)d_in[13];
    const float* fc2b  = (const float*)d_in[14];
    const float* fc3w  = (const float*)d_in[15];
    const float* fc3b  = (const float*)d_in[16];
    const int*   bidx  = (const int*)d_in[17];
    const int*   cidx  = (const int*)d_in[18];
    float* out = (float*)d_out;

    char* w = (char*)d_ws;
    constexpr size_t SZ_H  = (size_t)NN * 64 * 4;
    constexpr size_t SZ_HP = (size_t)NN * 128 * 4;
    constexpr size_t OFF_H  = 0;
    constexpr size_t OFF_HI = OFF_H + SZ_H;
    constexpr size_t OFF_HJ = OFF_HI + SZ_HP;
    constexpr size_t OFF_S  = OFF_HJ + SZ_HP;
    constexpr size_t OFF_SCSH1 = OFF_S + SZ_H;
    constexpr size_t OFF_SCSH2 = OFF_SCSH1 + 1024;
    constexpr size_t OFF_P1 = OFF_SCSH2 + 512;
    constexpr size_t OFF_P2 = OFF_P1 + (size_t)G_BOND * 256 * 4;
    constexpr size_t OFF_FE = OFF_P2 + (size_t)G_APPLY * 128 * 4;
    constexpr size_t OFF_FP = OFF_FE + 128 * 65 * 4;
    constexpr size_t OFF_T  = ((OFF_FP + 128 * 65 * 4) + 255) & ~(size_t)255;

    float* h      = (float*)(w + OFF_H);
    float* hi     = (float*)(w + OFF_HI);
    float* hj     = (float*)(w + OFF_HJ);
    float* sbuf   = (float*)(w + OFF_S);
    float* scsh1  = (float*)(w + OFF_SCSH1);
    float* scsh2  = (float*)(w + OFF_SCSH2);
    float* part1  = (float*)(w + OFF_P1);
    float* part2  = (float*)(w + OFF_P2);
    float* feats  = (float*)(w + OFF_FE);
    float* featsp = (float*)(w + OFF_FP);
    unsigned short* tbuf = (unsigned short*)(w + OFF_T);

    k_fc1<<<2500, 256, 0, stream>>>(site, fc1w, fc1b, h);
    for (int l = 0; l < LL; ++l) {
        const float* cw = convw + (size_t)l * 192 * 128;
        const float* cb = convb + l * 128;
        k_proj<<<1250, 256, 0, stream>>>(h, cw, cb, hi, hj);
        k_bond<<<G_BOND, 256, 0, stream>>>(bondf, cw + 128 * 128, hi, hj, bidx, tbuf, part1);
        k_fin1<<<1, 128, 0, stream>>>(part1, bn1g + l * 128, bn1b + l * 128, scsh1);
        k_apply<<<G_APPLY, 256, 0, stream>>>(tbuf, scsh1, sbuf, part2);
        k_fin2<<<1, 64, 0, stream>>>(part2, bn2g + l * 64, bn2b + l * 64, scsh2);
        k_upd<<<2500, 256, 0, stream>>>(h, sbuf, scsh2);
    }
    k_pool<<<128, 256, 0, stream>>>(h, cidx, feats);
    k_head1<<<1, 128, 0, stream>>>(feats, fap, topg, topb, featsp);
    k_head2<<<128, 128, 0, stream>>>(featsp, fc2w, fc2b, fc3w, fc3b, out);
}

// Round 2
// 896.062 us; speedup vs baseline: 1.4036x; 1.4036x over previous
//
#include <hip/hip_runtime.h>
#include <hip/hip_bf16.h>

// CGCNN forward. Decomposition:
//   t[n,m,:] = hi_proj[n,:] + hj_proj[idx[n,m],:] + bond[n,m,:]@w_b  (bias folded into hi_proj)
// k_bond: bf16 MFMA GEMM for the bond term + t assembly + bn1 partial stats + bf16 t store.
// BN finalization via two-stage parallel reductions (no single-block serial scans).

#define NN 40000
#define MM 12
#define AA 64
#define LL 3
#define CC 128
#define F0C 92
#define NBOND (NN*MM)
#define EPSBN 1e-5f

#define G_BOND 1250     // blocks for k_bond; 7500 tiles of 64 bonds -> 6 tiles/block
#define NTILE 7500
#define G_APPLY 1250    // blocks for k_apply; 2500 site-groups of 16 -> 2 iters/block
#define RED_B 125       // stage-A reduction blocks (1250 rows / 10)

typedef __attribute__((ext_vector_type(8))) short bf16x8;
typedef __attribute__((ext_vector_type(4))) float f32x4;

__device__ __forceinline__ float softplusf_(float x) {
    return fmaxf(x, 0.f) + log1pf(expf(-fabsf(x)));
}
__device__ __forceinline__ float sigmoidf_(float x) {
    return 1.f / (1.f + expf(-x));
}
__device__ __forceinline__ unsigned short f2bf(float f) {
    unsigned int u = __float_as_uint(f);
    unsigned int r = (u + 0x7fffu + ((u >> 16) & 1u)) >> 16;
    return (unsigned short)r;
}
__device__ __forceinline__ float bf2f(unsigned short s) {
    return __uint_as_float(((unsigned int)s) << 16);
}

// ---------------- fc1: h = site @ fc1_w + fc1_b  (40000x92 @ 92x64) ----------------
__global__ __launch_bounds__(256) void k_fc1(const float* __restrict__ site,
        const float* __restrict__ w, const float* __restrict__ b,
        float* __restrict__ h) {
    __shared__ float w_s[F0C][AA];
    __shared__ float x_s[16][F0C];
    int tid = threadIdx.x;
    for (int i = tid; i < F0C * AA; i += 256) w_s[i / AA][i % AA] = w[i];
    int n0 = blockIdx.x * 16;
    for (int i = tid; i < 16 * F0C; i += 256) x_s[i / F0C][i % F0C] = site[(size_t)n0 * F0C + i];
    __syncthreads();
    int d = tid & 63, ng = tid >> 6;
    float bb = b[d];
    float acc[4] = {bb, bb, bb, bb};
    #pragma unroll 4
    for (int k = 0; k < F0C; ++k) {
        float wv = w_s[k][d];
        acc[0] += x_s[ng][k] * wv;
        acc[1] += x_s[ng + 4][k] * wv;
        acc[2] += x_s[ng + 8][k] * wv;
        acc[3] += x_s[ng + 12][k] * wv;
    }
    #pragma unroll
    for (int rr = 0; rr < 4; ++rr)
        h[(size_t)(n0 + ng + rr * 4) * AA + d] = acc[rr];
}

// ---------------- proj: hi = h@w_i + bias, hj = h@w_j  (40000x64 @ 64x128 x2) ----------------
__global__ __launch_bounds__(256) void k_proj(const float* __restrict__ h,
        const float* __restrict__ convw, const float* __restrict__ convb,
        float* __restrict__ hi, float* __restrict__ hj) {
    __shared__ float w_s[64][256];   // cols 0..127 = w_i, 128..255 = w_j
    __shared__ float hT[64][36];     // transposed h tile [k][row]
    int tid = threadIdx.x;
    for (int i = tid; i < 64 * 256; i += 256) {
        int k = i >> 8, c = i & 255;
        w_s[k][c] = convw[(size_t)((c < 128 ? k : 64 + k)) * 128 + (c & 127)];
    }
    int row0 = blockIdx.x * 32;
    for (int i = tid; i < 2048; i += 256) {
        int r = i >> 6, k = i & 63;
        hT[k][r] = h[(size_t)(row0 + r) * 64 + k];
    }
    __syncthreads();
    int c0 = (tid & 63) * 4;
    int r0 = (tid >> 6) * 8;
    float acc[8][4];
    #pragma unroll
    for (int r = 0; r < 8; ++r)
        #pragma unroll
        for (int i = 0; i < 4; ++i) acc[r][i] = 0.f;
    #pragma unroll 4
    for (int k = 0; k < 64; ++k) {
        float4 w4 = *(const float4*)&w_s[k][c0];
        float4 ha = *(const float4*)&hT[k][r0];
        float4 hb = *(const float4*)&hT[k][r0 + 4];
        float wv[4] = {w4.x, w4.y, w4.z, w4.w};
        float hv[8] = {ha.x, ha.y, ha.z, ha.w, hb.x, hb.y, hb.z, hb.w};
        #pragma unroll
        for (int r = 0; r < 8; ++r)
            #pragma unroll
            for (int i = 0; i < 4; ++i) acc[r][i] += hv[r] * wv[i];
    }
    bool isHi = (c0 < 128);
    int cc = isHi ? c0 : c0 - 128;
    float4 cb4 = make_float4(0.f, 0.f, 0.f, 0.f);
    if (isHi) cb4 = *(const float4*)&convb[c0];
    float* dst = isHi ? hi : hj;
    #pragma unroll
    for (int r = 0; r < 8; ++r) {
        int n = row0 + r0 + r;
        float4 o = make_float4(acc[r][0] + cb4.x, acc[r][1] + cb4.y,
                               acc[r][2] + cb4.z, acc[r][3] + cb4.w);
        *(float4*)&dst[(size_t)n * 128 + cc] = o;
    }
}

// ---------------- bond GEMM (bf16 MFMA) + t assembly + bn1 partial stats ----------------
__global__ __launch_bounds__(256) void k_bond(const float* __restrict__ bf,
        const float* __restrict__ wb,
        const float* __restrict__ hi, const float* __restrict__ hj,
        const int* __restrict__ bidx,
        unsigned short* __restrict__ tbuf,
        float* __restrict__ part1) {
    __shared__ unsigned short wbT[128][72];   // [col][k] bf16, rows padded to 72 (144B)
    __shared__ unsigned short A_lds[64][72];  // [bond][k] bf16
    __shared__ unsigned short t_lds[64][136]; // [bond][col] bf16 staging for coalesced store
    __shared__ float red[4][132];

    int tid = threadIdx.x;
    int lane = tid & 63, w = tid >> 6;
    int l15 = lane & 15, l4 = lane >> 4;

    // stage wbT: wb is [64][128] f32 row-major -> wbT[c][k] bf16
    for (int i = tid; i < 64 * 128; i += 256) {
        int k = i >> 7, c = i & 127;
        wbT[c][k] = f2bf(wb[i]);
    }
    __syncthreads();

    // preload all 16 B-fragments (reused for every tile)
    bf16x8 bfr[2][8];
    #pragma unroll
    for (int kh = 0; kh < 2; ++kh)
        #pragma unroll
        for (int ct = 0; ct < 8; ++ct)
            bfr[kh][ct] = *(const bf16x8*)&wbT[ct * 16 + l15][kh * 32 + l4 * 8];

    float suml[8], sql[8];
    #pragma unroll
    for (int ct = 0; ct < 8; ++ct) { suml[ct] = 0.f; sql[ct] = 0.f; }

    for (int tile = blockIdx.x; tile < NTILE; tile += G_BOND) {
        int bond0 = tile * 64;
        __syncthreads();  // t_lds writeout of previous tile done
        // stage A: 64 bonds x 64 k, f32 -> bf16
        {
            int r = tid >> 4, kq = (tid & 15) * 4;
            #pragma unroll
            for (int rr = 0; rr < 4; ++rr) {
                float4 v = *(const float4*)&bf[((size_t)(bond0 + r + rr * 16)) * 64 + kq];
                ushort4 u;
                u.x = f2bf(v.x); u.y = f2bf(v.y); u.z = f2bf(v.z); u.w = f2bf(v.w);
                *(ushort4*)&A_lds[r + rr * 16][kq] = u;
            }
        }
        __syncthreads();

        f32x4 acc[8];
        #pragma unroll
        for (int ct = 0; ct < 8; ++ct) acc[ct] = (f32x4){0.f, 0.f, 0.f, 0.f};
        #pragma unroll
        for (int kh = 0; kh < 2; ++kh) {
            bf16x8 a = *(const bf16x8*)&A_lds[w * 16 + l15][kh * 32 + l4 * 8];
            #pragma unroll
            for (int ct = 0; ct < 8; ++ct)
                acc[ct] = __builtin_amdgcn_mfma_f32_16x16x32_bf16(a, bfr[kh][ct], acc[ct], 0, 0, 0);
        }

        // epilogue: add hi/hj, stats, stage t into LDS
        int rbase = w * 16 + l4 * 4;
        #pragma unroll
        for (int reg = 0; reg < 4; ++reg) {
            int bond = bond0 + rbase + reg;
            int n = bond / MM;
            int j = bidx[bond];
            const float* hin = hi + (size_t)n * 128;
            const float* hjn = hj + (size_t)j * 128;
            #pragma unroll
            for (int ct = 0; ct < 8; ++ct) {
                int col = ct * 16 + l15;
                float t = acc[ct][reg] + hin[col] + hjn[col];
                suml[ct] += t;
                sql[ct] += t * t;
                t_lds[rbase + reg][col] = f2bf(t);
            }
        }
        __syncthreads();
        // coalesced writeout: 16B per thread
        for (int i = tid; i < 64 * 16; i += 256) {
            int r = i >> 4, c8 = (i & 15) * 8;
            bf16x8 u = *(const bf16x8*)&t_lds[r][c8];
            *(bf16x8*)&tbuf[((size_t)(bond0 + r)) * 128 + c8] = u;
        }
    }

    // stats reduce: per-lane suml[ct] covers col = ct*16+l15 over its rows.
    #pragma unroll
    for (int ct = 0; ct < 8; ++ct) {
        float s = suml[ct], q = sql[ct];
        s += __shfl_xor(s, 16); s += __shfl_xor(s, 32);
        q += __shfl_xor(q, 16); q += __shfl_xor(q, 32);
        suml[ct] = s; sql[ct] = q;
    }
    __syncthreads();
    if (l4 == 0) {
        #pragma unroll
        for (int ct = 0; ct < 8; ++ct) red[w][ct * 16 + l15] = suml[ct];
    }
    __syncthreads();
    if (tid < 128)
        part1[(size_t)blockIdx.x * 256 + tid] = red[0][tid] + red[1][tid] + red[2][tid] + red[3][tid];
    __syncthreads();
    if (l4 == 0) {
        #pragma unroll
        for (int ct = 0; ct < 8; ++ct) red[w][ct * 16 + l15] = sql[ct];
    }
    __syncthreads();
    if (tid < 128)
        part1[(size_t)blockIdx.x * 256 + 128 + tid] = red[0][tid] + red[1][tid] + red[2][tid] + red[3][tid];
}

// ---------------- stage-A reductions: [1250][C] -> [125][C] ----------------
__global__ __launch_bounds__(256) void k_red1(const float* __restrict__ in, float* __restrict__ out) {
    int tid = threadIdx.x, b = blockIdx.x;
    float acc = 0.f;
    for (int r = b * 10; r < b * 10 + 10; ++r) acc += in[(size_t)r * 256 + tid];
    out[(size_t)b * 256 + tid] = acc;
}
__global__ __launch_bounds__(128) void k_red2(const float* __restrict__ in, float* __restrict__ out) {
    int tid = threadIdx.x, b = blockIdx.x;
    float acc = 0.f;
    for (int r = b * 10; r < b * 10 + 10; ++r) acc += in[(size_t)r * 128 + tid];
    out[(size_t)b * 128 + tid] = acc;
}

// ---------------- finalize bn1 -> scale/shift ----------------
__global__ __launch_bounds__(256) void k_fin1(const float* __restrict__ partA, const float* __restrict__ g,
                       const float* __restrict__ b, float* __restrict__ scsh) {
    __shared__ float sm[256];
    int tid = threadIdx.x;
    float acc = 0.f;
    for (int r = 0; r < RED_B; ++r) acc += partA[(size_t)r * 256 + tid];
    sm[tid] = acc;
    __syncthreads();
    if (tid < 128) {
        float m = sm[tid] / (float)NBOND;
        float v = sm[128 + tid] / (float)NBOND - m * m;
        float sc = g[tid] * rsqrtf(v + EPSBN);
        scsh[tid] = sc;
        scsh[128 + tid] = b[tid] - m * sc;
    }
}

// ---------------- finalize bn2 ----------------
__global__ __launch_bounds__(128) void k_fin2(const float* __restrict__ partB, const float* __restrict__ g,
                       const float* __restrict__ b, float* __restrict__ scsh2) {
    __shared__ float sm[128];
    int tid = threadIdx.x;
    float acc = 0.f;
    for (int r = 0; r < RED_B; ++r) acc += partB[(size_t)r * 128 + tid];
    sm[tid] = acc;
    __syncthreads();
    if (tid < 64) {
        float m = sm[tid] / (float)NN;
        float v = sm[64 + tid] / (float)NN - m * m;
        float sc = g[tid] * rsqrtf(v + EPSBN);
        scsh2[tid] = sc;
        scsh2[64 + tid] = b[tid] - m * sc;
    }
}

// ---------------- apply bn1 + gated sum over m + bn2 partial stats ----------------
__global__ __launch_bounds__(256) void k_apply(const unsigned short* __restrict__ tbuf,
        const float* __restrict__ scsh, float* __restrict__ s_out,
        float* __restrict__ part2) {
    __shared__ float red[16][68];
    int tid = threadIdx.x;
    int c4 = (tid & 15) * 4, sg = tid >> 4;
    float scf[4], shf[4], scc[4], shc[4];
    #pragma unroll
    for (int j = 0; j < 4; ++j) {
        scf[j] = scsh[c4 + j];       shf[j] = scsh[128 + c4 + j];
        scc[j] = scsh[64 + c4 + j];  shc[j] = scsh[192 + c4 + j];
    }
    float sum[4] = {0, 0, 0, 0}, sq[4] = {0, 0, 0, 0};
    for (int q = blockIdx.x; q < NN / 16; q += G_APPLY) {
        int n = q * 16 + sg;
        const unsigned short* tb = tbuf + (size_t)n * (MM * 128);
        float sacc[4] = {0, 0, 0, 0};
        #pragma unroll
        for (int m = 0; m < MM; ++m) {
            ushort4 f4 = *(const ushort4*)&tb[m * 128 + c4];
            ushort4 s4 = *(const ushort4*)&tb[m * 128 + 64 + c4];
            float ff[4] = {bf2f(f4.x), bf2f(f4.y), bf2f(f4.z), bf2f(f4.w)};
            float ss[4] = {bf2f(s4.x), bf2f(s4.y), bf2f(s4.z), bf2f(s4.w)};
            #pragma unroll
            for (int j = 0; j < 4; ++j)
                sacc[j] += sigmoidf_(scf[j] * ff[j] + shf[j]) * softplusf_(scc[j] * ss[j] + shc[j]);
        }
        *(float4*)&s_out[(size_t)n * 64 + c4] = make_float4(sacc[0], sacc[1], sacc[2], sacc[3]);
        #pragma unroll
        for (int j = 0; j < 4; ++j) { sum[j] += sacc[j]; sq[j] += sacc[j] * sacc[j]; }
    }
    #pragma unroll
    for (int j = 0; j < 4; ++j) red[sg][c4 + j] = sum[j];
    __syncthreads();
    if (tid < 64) {
        float t = 0.f;
        #pragma unroll
        for (int g = 0; g < 16; ++g) t += red[g][tid];
        part2[(size_t)blockIdx.x * 128 + tid] = t;
    }
    __syncthreads();
    #pragma unroll
    for (int j = 0; j < 4; ++j) red[sg][c4 + j] = sq[j];
    __syncthreads();
    if (tid < 64) {
        float t = 0.f;
        #pragma unroll
        for (int g = 0; g < 16; ++g) t += red[g][tid];
        part2[(size_t)blockIdx.x * 128 + 64 + tid] = t;
    }
}

// ---------------- h = softplus(h + bn2(s)) ----------------
__global__ __launch_bounds__(256) void k_upd(float* __restrict__ h, const float* __restrict__ s,
        const float* __restrict__ scsh2) {
    size_t i = ((size_t)blockIdx.x * 256 + threadIdx.x) * 4;
    int c0 = (int)(i & 63);
    float4 hv = *(const float4*)&h[i];
    float4 sv = *(const float4*)&s[i];
    float4 o;
    o.x = softplusf_(hv.x + scsh2[c0 + 0] * sv.x + scsh2[64 + c0 + 0]);
    o.y = softplusf_(hv.y + scsh2[c0 + 1] * sv.y + scsh2[64 + c0 + 1]);
    o.z = softplusf_(hv.z + scsh2[c0 + 2] * sv.z + scsh2[64 + c0 + 2]);
    o.w = softplusf_(hv.w + scsh2[c0 + 3] * sv.w + scsh2[64 + c0 + 3]);
    *(float4*)&h[i] = o;
}

// ---------------- pooling: segment mean (crystal_idx sorted) ----------------
__device__ __forceinline__ int lbound(const int* a, int n, int v) {
    int lo = 0, hi = n;
    while (lo < hi) { int mid = (lo + hi) >> 1; if (a[mid] < v) lo = mid + 1; else hi = mid; }
    return lo;
}

__global__ __launch_bounds__(256) void k_pool(const float* __restrict__ h,
        const int* __restrict__ cidx, float* __restrict__ feats) {
    __shared__ float red[4][68];
    __shared__ int bounds[2];
    int c = blockIdx.x, tid = threadIdx.x;
    if (tid == 0) {
        bounds[0] = lbound(cidx, NN, c);
        bounds[1] = lbound(cidx, NN, c + 1);
    }
    __syncthreads();
    int lo = bounds[0], hi = bounds[1];
    int d = tid & 63, g = tid >> 6;
    float acc = 0;
    for (int n = lo + g; n < hi; n += 4) acc += h[(size_t)n * 64 + d];
    red[g][d] = acc;
    __syncthreads();
    if (tid < 64) {
        float t = red[0][tid] + red[1][tid] + red[2][tid] + red[3][tid];
        int cnt = hi - lo;
        feats[(size_t)c * 65 + tid] = t / (float)(cnt > 0 ? cnt : 1);
    }
}

// ---------------- head part 1: fill col 64, top BN + softplus ----------------
__global__ __launch_bounds__(128) void k_head1(float* __restrict__ feats, const float* __restrict__ fap,
        const float* __restrict__ g, const float* __restrict__ b, float* __restrict__ featsp) {
    int tid = threadIdx.x;
    if (tid < CC) feats[(size_t)tid * 65 + 64] = fap[tid];
    __syncthreads();
    if (tid < 65) {
        float s = 0;
        for (int r = 0; r < CC; ++r) s += feats[r * 65 + tid];
        float m = s / (float)CC;
        float v = 0;
        for (int r = 0; r < CC; ++r) { float d = feats[r * 65 + tid] - m; v += d * d; }
        v /= (float)CC;
        float sc = g[tid] * rsqrtf(v + EPSBN);
        float sh = b[tid] - m * sc;
        for (int r = 0; r < CC; ++r)
            featsp[r * 65 + tid] = softplusf_(sc * feats[r * 65 + tid] + sh);
    }
}

// ---------------- head part 2: fc2 + softplus + fc3 ----------------
__global__ __launch_bounds__(128) void k_head2(const float* __restrict__ featsp,
        const float* __restrict__ fc2w, const float* __restrict__ fc2b,
        const float* __restrict__ fc3w, const float* __restrict__ fc3b,
        float* __restrict__ out) {
    __shared__ float fr[65];
    __shared__ float red[128];
    int r = blockIdx.x, tid = threadIdx.x;
    if (tid < 65) fr[tid] = featsp[(size_t)r * 65 + tid];
    __syncthreads();
    float acc = fc2b[tid];
    for (int k = 0; k < 65; ++k) acc += fr[k] * fc2w[k * 128 + tid];
    red[tid] = softplusf_(acc) * fc3w[tid];
    __syncthreads();
    for (int st = 64; st > 0; st >>= 1) {
        if (tid < st) red[tid] += red[tid + st];
        __syncthreads();
    }
    if (tid == 0) out[r] = red[0] + fc3b[0];
}

extern "C" void kernel_launch(void* const* d_in, const int* in_sizes, int n_in,
                              void* d_out, int out_size, void* d_ws, size_t ws_size,
                              hipStream_t stream) {
    const float* site  = (const float*)d_in[0];
    const float* bondf = (const float*)d_in[1];
    const float* fap   = (const float*)d_in[2];
    const float* fc1w  = (const float*)d_in[3];
    const float* fc1b  = (const float*)d_in[4];
    const float* convw = (const float*)d_in[5];
    const float* convb = (const float*)d_in[6];
    const float* bn1g  = (const float*)d_in[7];
    const float* bn1b  = (const float*)d_in[8];
    const float* bn2g  = (const float*)d_in[9];
    const float* bn2b  = (const float*)d_in[10];
    const float* topg  = (const float*)d_in[11];
    const float* topb  = (const float*)d_in[12];
    const float* fc2w  = (const float*)d_in[13];
    const float* fc2b  = (const float*)d_in[14];
    const float* fc3w  = (const float*)d_in[15];
    const float* fc3b  = (const float*)d_in[16];
    const int*   bidx  = (const int*)d_in[17];
    const int*   cidx  = (const int*)d_in[18];
    float* out = (float*)d_out;

    char* w = (char*)d_ws;
    constexpr size_t SZ_H  = (size_t)NN * 64 * 4;
    constexpr size_t SZ_HP = (size_t)NN * 128 * 4;
    constexpr size_t OFF_H  = 0;
    constexpr size_t OFF_HI = OFF_H + SZ_H;
    constexpr size_t OFF_HJ = OFF_HI + SZ_HP;
    constexpr size_t OFF_S  = OFF_HJ + SZ_HP;
    constexpr size_t OFF_SCSH1 = OFF_S + SZ_H;
    constexpr size_t OFF_SCSH2 = OFF_SCSH1 + 1024;
    constexpr size_t OFF_P1 = OFF_SCSH2 + 512;
    constexpr size_t OFF_P2 = OFF_P1 + (size_t)G_BOND * 256 * 4;
    constexpr size_t OFF_PA = OFF_P2 + (size_t)G_APPLY * 128 * 4;
    constexpr size_t OFF_PB = OFF_PA + (size_t)RED_B * 256 * 4;
    constexpr size_t OFF_FE = OFF_PB + (size_t)RED_B * 128 * 4;
    constexpr size_t OFF_FP = OFF_FE + 128 * 65 * 4;
    constexpr size_t OFF_T  = ((OFF_FP + 128 * 65 * 4) + 255) & ~(size_t)255;

    float* h      = (float*)(w + OFF_H);
    float* hi     = (float*)(w + OFF_HI);
    float* hj     = (float*)(w + OFF_HJ);
    float* sbuf   = (float*)(w + OFF_S);
    float* scsh1  = (float*)(w + OFF_SCSH1);
    float* scsh2  = (float*)(w + OFF_SCSH2);
    float* part1  = (float*)(w + OFF_P1);
    float* part2  = (float*)(w + OFF_P2);
    float* partA  = (float*)(w + OFF_PA);
    float* partB  = (float*)(w + OFF_PB);
    float* feats  = (float*)(w + OFF_FE);
    float* featsp = (float*)(w + OFF_FP);
    unsigned short* tbuf = (unsigned short*)(w + OFF_T);

    k_fc1<<<2500, 256, 0, stream>>>(site, fc1w, fc1b, h);
    for (int l = 0; l < LL; ++l) {
        const float* cw = convw + (size_t)l * 192 * 128;
        const float* cb = convb + l * 128;
        k_proj<<<1250, 256, 0, stream>>>(h, cw, cb, hi, hj);
        k_bond<<<G_BOND, 256, 0, stream>>>(bondf, cw + 128 * 128, hi, hj, bidx, tbuf, part1);
        k_red1<<<RED_B, 256, 0, stream>>>(part1, partA);
        k_fin1<<<1, 256, 0, stream>>>(partA, bn1g + l * 128, bn1b + l * 128, scsh1);
        k_apply<<<G_APPLY, 256, 0, stream>>>(tbuf, scsh1, sbuf, part2);
        k_red2<<<RED_B, 128, 0, stream>>>(part2, partB);
        k_fin2<<<1, 128, 0, stream>>>(partB, bn2g + l * 64, bn2b + l * 64, scsh2);
        k_upd<<<2500, 256, 0, stream>>>(h, sbuf, scsh2);
    }
    k_pool<<<128, 256, 0, stream>>>(h, cidx, feats);
    k_head1<<<1, 128, 0, stream>>>(feats, fap, topg, topb, featsp);
    k_head2<<<128, 128, 0, stream>>>(featsp, fc2w, fc2b, fc3w, fc3b, out);
}

// Round 3
// 557.186 us; speedup vs baseline: 2.2573x; 1.6082x over previous
//
#include <hip/hip_runtime.h>
#include <hip/hip_bf16.h>

// CGCNN forward. Decomposition:
//   t[n,m,:] = hi_proj[n,:] + hj_proj[idx[n,m],:] + bond[n,m,:]@w_b  (bias folded into hi_proj)
// k_bond: bf16 MFMA GEMM for the bond term + t assembly + bn1 partial stats + bf16 t store.
// BN finalization via two-stage parallel reductions.
// Transcendentals via HW v_exp_f32/v_log_f32/v_rcp_f32 (libm expf/log1pf/fdiv was the
// round-2 bottleneck: k_apply 84% VALUBusy at 7% HBM).

#define NN 40000
#define MM 12
#define AA 64
#define LL 3
#define CC 128
#define F0C 92
#define NBOND (NN*MM)
#define EPSBN 1e-5f

#define G_BOND 1250     // blocks for k_bond; 7500 tiles of 64 bonds -> 6 tiles/block
#define NTILE 7500
#define G_APPLY 1250    // blocks for k_apply; 2500 site-groups of 16 -> 2 iters/block
#define RED_B 125       // stage-A reduction blocks (1250 rows / 10)

#define L2E 1.4426950408889634f
#define LN2 0.6931471805599453f

typedef __attribute__((ext_vector_type(8))) short bf16x8;
typedef __attribute__((ext_vector_type(4))) float f32x4;

__device__ __forceinline__ float softplusf_(float x) {
    float e = __builtin_amdgcn_exp2f(-fabsf(x) * L2E);
    return fmaxf(x, 0.f) + __builtin_amdgcn_logf(1.f + e) * LN2;
}
__device__ __forceinline__ float sigmoidf_(float x) {
    return __builtin_amdgcn_rcpf(1.f + __builtin_amdgcn_exp2f(-x * L2E));
}
__device__ __forceinline__ unsigned short f2bf(float f) {
    unsigned int u = __float_as_uint(f);
    unsigned int r = (u + 0x7fffu + ((u >> 16) & 1u)) >> 16;
    return (unsigned short)r;
}
__device__ __forceinline__ float bf2f(unsigned short s) {
    return __uint_as_float(((unsigned int)s) << 16);
}

// ---------------- bond features f32 -> bf16, once ----------------
__global__ __launch_bounds__(256) void k_cvt(const float* __restrict__ in,
        unsigned short* __restrict__ out) {
    size_t i = ((size_t)blockIdx.x * 256 + threadIdx.x) * 8;
    float4 a = *(const float4*)&in[i];
    float4 b = *(const float4*)&in[i + 4];
    ushort4 ua, ub;
    ua.x = f2bf(a.x); ua.y = f2bf(a.y); ua.z = f2bf(a.z); ua.w = f2bf(a.w);
    ub.x = f2bf(b.x); ub.y = f2bf(b.y); ub.z = f2bf(b.z); ub.w = f2bf(b.w);
    *(ushort4*)&out[i] = ua;
    *(ushort4*)&out[i + 4] = ub;
}

// ---------------- fc1: h = site @ fc1_w + fc1_b  (40000x92 @ 92x64) ----------------
__global__ __launch_bounds__(256) void k_fc1(const float* __restrict__ site,
        const float* __restrict__ w, const float* __restrict__ b,
        float* __restrict__ h) {
    __shared__ float w_s[F0C][AA];
    __shared__ float x_s[16][F0C];
    int tid = threadIdx.x;
    for (int i = tid; i < F0C * AA; i += 256) w_s[i / AA][i % AA] = w[i];
    int n0 = blockIdx.x * 16;
    for (int i = tid; i < 16 * F0C; i += 256) x_s[i / F0C][i % F0C] = site[(size_t)n0 * F0C + i];
    __syncthreads();
    int d = tid & 63, ng = tid >> 6;
    float bb = b[d];
    float acc[4] = {bb, bb, bb, bb};
    #pragma unroll 4
    for (int k = 0; k < F0C; ++k) {
        float wv = w_s[k][d];
        acc[0] += x_s[ng][k] * wv;
        acc[1] += x_s[ng + 4][k] * wv;
        acc[2] += x_s[ng + 8][k] * wv;
        acc[3] += x_s[ng + 12][k] * wv;
    }
    #pragma unroll
    for (int rr = 0; rr < 4; ++rr)
        h[(size_t)(n0 + ng + rr * 4) * AA + d] = acc[rr];
}

// ---------------- proj: hi = h@w_i + bias, hj = h@w_j  (40000x64 @ 64x128 x2) ----------------
__global__ __launch_bounds__(256) void k_proj(const float* __restrict__ h,
        const float* __restrict__ convw, const float* __restrict__ convb,
        float* __restrict__ hi, float* __restrict__ hj) {
    __shared__ float w_s[64][256];   // cols 0..127 = w_i, 128..255 = w_j
    __shared__ float hT[64][36];     // transposed h tile [k][row]
    int tid = threadIdx.x;
    for (int i = tid; i < 64 * 256; i += 256) {
        int k = i >> 8, c = i & 255;
        w_s[k][c] = convw[(size_t)((c < 128 ? k : 64 + k)) * 128 + (c & 127)];
    }
    int row0 = blockIdx.x * 32;
    for (int i = tid; i < 2048; i += 256) {
        int r = i >> 6, k = i & 63;
        hT[k][r] = h[(size_t)(row0 + r) * 64 + k];
    }
    __syncthreads();
    int c0 = (tid & 63) * 4;
    int r0 = (tid >> 6) * 8;
    float acc[8][4];
    #pragma unroll
    for (int r = 0; r < 8; ++r)
        #pragma unroll
        for (int i = 0; i < 4; ++i) acc[r][i] = 0.f;
    #pragma unroll 4
    for (int k = 0; k < 64; ++k) {
        float4 w4 = *(const float4*)&w_s[k][c0];
        float4 ha = *(const float4*)&hT[k][r0];
        float4 hb = *(const float4*)&hT[k][r0 + 4];
        float wv[4] = {w4.x, w4.y, w4.z, w4.w};
        float hv[8] = {ha.x, ha.y, ha.z, ha.w, hb.x, hb.y, hb.z, hb.w};
        #pragma unroll
        for (int r = 0; r < 8; ++r)
            #pragma unroll
            for (int i = 0; i < 4; ++i) acc[r][i] += hv[r] * wv[i];
    }
    bool isHi = (c0 < 128);
    int cc = isHi ? c0 : c0 - 128;
    float4 cb4 = make_float4(0.f, 0.f, 0.f, 0.f);
    if (isHi) cb4 = *(const float4*)&convb[c0];
    float* dst = isHi ? hi : hj;
    #pragma unroll
    for (int r = 0; r < 8; ++r) {
        int n = row0 + r0 + r;
        float4 o = make_float4(acc[r][0] + cb4.x, acc[r][1] + cb4.y,
                               acc[r][2] + cb4.z, acc[r][3] + cb4.w);
        *(float4*)&dst[(size_t)n * 128 + cc] = o;
    }
}

// ---------------- bond GEMM (bf16 MFMA) + t assembly + bn1 partial stats ----------------
template<bool BFQ>
__global__ __launch_bounds__(256) void k_bond(const float* __restrict__ bf,
        const unsigned short* __restrict__ bfq,
        const float* __restrict__ wb,
        const float* __restrict__ hi, const float* __restrict__ hj,
        const int* __restrict__ bidx,
        unsigned short* __restrict__ tbuf,
        float* __restrict__ part1) {
    __shared__ unsigned short wbT[128][72];   // [col][k] bf16
    __shared__ unsigned short A_lds[64][72];  // [bond][k] bf16
    __shared__ unsigned short t_lds[64][136]; // [bond][col] bf16 staging
    __shared__ float red[4][132];

    int tid = threadIdx.x;
    int lane = tid & 63, w = tid >> 6;
    int l15 = lane & 15, l4 = lane >> 4;

    for (int i = tid; i < 64 * 128; i += 256) {
        int k = i >> 7, c = i & 127;
        wbT[c][k] = f2bf(wb[i]);
    }
    __syncthreads();

    bf16x8 bfr[2][8];
    #pragma unroll
    for (int kh = 0; kh < 2; ++kh)
        #pragma unroll
        for (int ct = 0; ct < 8; ++ct)
            bfr[kh][ct] = *(const bf16x8*)&wbT[ct * 16 + l15][kh * 32 + l4 * 8];

    float suml[8], sql[8];
    #pragma unroll
    for (int ct = 0; ct < 8; ++ct) { suml[ct] = 0.f; sql[ct] = 0.f; }

    for (int tile = blockIdx.x; tile < NTILE; tile += G_BOND) {
        int bond0 = tile * 64;
        __syncthreads();
        if constexpr (BFQ) {
            int r = tid >> 3, c8 = (tid & 7) * 8;
            #pragma unroll
            for (int rr = 0; rr < 2; ++rr) {
                bf16x8 v = *(const bf16x8*)&bfq[((size_t)(bond0 + r + rr * 32)) * 64 + c8];
                *(bf16x8*)&A_lds[r + rr * 32][c8] = v;
            }
        } else {
            int r = tid >> 4, kq = (tid & 15) * 4;
            #pragma unroll
            for (int rr = 0; rr < 4; ++rr) {
                float4 v = *(const float4*)&bf[((size_t)(bond0 + r + rr * 16)) * 64 + kq];
                ushort4 u;
                u.x = f2bf(v.x); u.y = f2bf(v.y); u.z = f2bf(v.z); u.w = f2bf(v.w);
                *(ushort4*)&A_lds[r + rr * 16][kq] = u;
            }
        }
        __syncthreads();

        f32x4 acc[8];
        #pragma unroll
        for (int ct = 0; ct < 8; ++ct) acc[ct] = (f32x4){0.f, 0.f, 0.f, 0.f};
        #pragma unroll
        for (int kh = 0; kh < 2; ++kh) {
            bf16x8 a = *(const bf16x8*)&A_lds[w * 16 + l15][kh * 32 + l4 * 8];
            #pragma unroll
            for (int ct = 0; ct < 8; ++ct)
                acc[ct] = __builtin_amdgcn_mfma_f32_16x16x32_bf16(a, bfr[kh][ct], acc[ct], 0, 0, 0);
        }

        int rbase = w * 16 + l4 * 4;
        #pragma unroll
        for (int reg = 0; reg < 4; ++reg) {
            int bond = bond0 + rbase + reg;
            int n = bond / MM;
            int j = bidx[bond];
            const float* hin = hi + (size_t)n * 128;
            const float* hjn = hj + (size_t)j * 128;
            #pragma unroll
            for (int ct = 0; ct < 8; ++ct) {
                int col = ct * 16 + l15;
                float t = acc[ct][reg] + hin[col] + hjn[col];
                suml[ct] += t;
                sql[ct] += t * t;
                t_lds[rbase + reg][col] = f2bf(t);
            }
        }
        __syncthreads();
        for (int i = tid; i < 64 * 16; i += 256) {
            int r = i >> 4, c8 = (i & 15) * 8;
            bf16x8 u = *(const bf16x8*)&t_lds[r][c8];
            *(bf16x8*)&tbuf[((size_t)(bond0 + r)) * 128 + c8] = u;
        }
    }

    #pragma unroll
    for (int ct = 0; ct < 8; ++ct) {
        float s = suml[ct], q = sql[ct];
        s += __shfl_xor(s, 16); s += __shfl_xor(s, 32);
        q += __shfl_xor(q, 16); q += __shfl_xor(q, 32);
        suml[ct] = s; sql[ct] = q;
    }
    __syncthreads();
    if (l4 == 0) {
        #pragma unroll
        for (int ct = 0; ct < 8; ++ct) red[w][ct * 16 + l15] = suml[ct];
    }
    __syncthreads();
    if (tid < 128)
        part1[(size_t)blockIdx.x * 256 + tid] = red[0][tid] + red[1][tid] + red[2][tid] + red[3][tid];
    __syncthreads();
    if (l4 == 0) {
        #pragma unroll
        for (int ct = 0; ct < 8; ++ct) red[w][ct * 16 + l15] = sql[ct];
    }
    __syncthreads();
    if (tid < 128)
        part1[(size_t)blockIdx.x * 256 + 128 + tid] = red[0][tid] + red[1][tid] + red[2][tid] + red[3][tid];
}

// ---------------- stage-A reductions ----------------
__global__ __launch_bounds__(256) void k_red1(const float* __restrict__ in, float* __restrict__ out) {
    int tid = threadIdx.x, b = blockIdx.x;
    float acc = 0.f;
    for (int r = b * 10; r < b * 10 + 10; ++r) acc += in[(size_t)r * 256 + tid];
    out[(size_t)b * 256 + tid] = acc;
}
__global__ __launch_bounds__(128) void k_red2(const float* __restrict__ in, float* __restrict__ out) {
    int tid = threadIdx.x, b = blockIdx.x;
    float acc = 0.f;
    for (int r = b * 10; r < b * 10 + 10; ++r) acc += in[(size_t)r * 128 + tid];
    out[(size_t)b * 128 + tid] = acc;
}

// ---------------- finalize bn1 ----------------
__global__ __launch_bounds__(256) void k_fin1(const float* __restrict__ partA, const float* __restrict__ g,
                       const float* __restrict__ b, float* __restrict__ scsh) {
    __shared__ float sm[256];
    int tid = threadIdx.x;
    float acc = 0.f;
    for (int r = 0; r < RED_B; ++r) acc += partA[(size_t)r * 256 + tid];
    sm[tid] = acc;
    __syncthreads();
    if (tid < 128) {
        float m = sm[tid] / (float)NBOND;
        float v = sm[128 + tid] / (float)NBOND - m * m;
        float sc = g[tid] * rsqrtf(v + EPSBN);
        scsh[tid] = sc;
        scsh[128 + tid] = b[tid] - m * sc;
    }
}

// ---------------- finalize bn2 ----------------
__global__ __launch_bounds__(128) void k_fin2(const float* __restrict__ partB, const float* __restrict__ g,
                       const float* __restrict__ b, float* __restrict__ scsh2) {
    __shared__ float sm[128];
    int tid = threadIdx.x;
    float acc = 0.f;
    for (int r = 0; r < RED_B; ++r) acc += partB[(size_t)r * 128 + tid];
    sm[tid] = acc;
    __syncthreads();
    if (tid < 64) {
        float m = sm[tid] / (float)NN;
        float v = sm[64 + tid] / (float)NN - m * m;
        float sc = g[tid] * rsqrtf(v + EPSBN);
        scsh2[tid] = sc;
        scsh2[64 + tid] = b[tid] - m * sc;
    }
}

// ---------------- apply bn1 + gated sum over m + bn2 partial stats ----------------
__global__ __launch_bounds__(256) void k_apply(const unsigned short* __restrict__ tbuf,
        const float* __restrict__ scsh, float* __restrict__ s_out,
        float* __restrict__ part2) {
    __shared__ float red[16][68];
    int tid = threadIdx.x;
    int c4 = (tid & 15) * 4, sg = tid >> 4;
    float scf[4], shf[4], scc[4], shc[4];
    #pragma unroll
    for (int j = 0; j < 4; ++j) {
        scf[j] = scsh[c4 + j];       shf[j] = scsh[128 + c4 + j];
        scc[j] = scsh[64 + c4 + j];  shc[j] = scsh[192 + c4 + j];
    }
    float sum[4] = {0, 0, 0, 0}, sq[4] = {0, 0, 0, 0};
    for (int q = blockIdx.x; q < NN / 16; q += G_APPLY) {
        int n = q * 16 + sg;
        const unsigned short* tb = tbuf + (size_t)n * (MM * 128);
        float sacc[4] = {0, 0, 0, 0};
        #pragma unroll
        for (int m = 0; m < MM; ++m) {
            ushort4 f4 = *(const ushort4*)&tb[m * 128 + c4];
            ushort4 s4 = *(const ushort4*)&tb[m * 128 + 64 + c4];
            float ff[4] = {bf2f(f4.x), bf2f(f4.y), bf2f(f4.z), bf2f(f4.w)};
            float ss[4] = {bf2f(s4.x), bf2f(s4.y), bf2f(s4.z), bf2f(s4.w)};
            #pragma unroll
            for (int j = 0; j < 4; ++j)
                sacc[j] += sigmoidf_(scf[j] * ff[j] + shf[j]) * softplusf_(scc[j] * ss[j] + shc[j]);
        }
        *(float4*)&s_out[(size_t)n * 64 + c4] = make_float4(sacc[0], sacc[1], sacc[2], sacc[3]);
        #pragma unroll
        for (int j = 0; j < 4; ++j) { sum[j] += sacc[j]; sq[j] += sacc[j] * sacc[j]; }
    }
    #pragma unroll
    for (int j = 0; j < 4; ++j) red[sg][c4 + j] = sum[j];
    __syncthreads();
    if (tid < 64) {
        float t = 0.f;
        #pragma unroll
        for (int g = 0; g < 16; ++g) t += red[g][tid];
        part2[(size_t)blockIdx.x * 128 + tid] = t;
    }
    __syncthreads();
    #pragma unroll
    for (int j = 0; j < 4; ++j) red[sg][c4 + j] = sq[j];
    __syncthreads();
    if (tid < 64) {
        float t = 0.f;
        #pragma unroll
        for (int g = 0; g < 16; ++g) t += red[g][tid];
        part2[(size_t)blockIdx.x * 128 + 64 + tid] = t;
    }
}

// ---------------- h = softplus(h + bn2(s)) ----------------
__global__ __launch_bounds__(256) void k_upd(float* __restrict__ h, const float* __restrict__ s,
        const float* __restrict__ scsh2) {
    size_t i = ((size_t)blockIdx.x * 256 + threadIdx.x) * 4;
    int c0 = (int)(i & 63);
    float4 hv = *(const float4*)&h[i];
    float4 sv = *(const float4*)&s[i];
    float4 o;
    o.x = softplusf_(hv.x + scsh2[c0 + 0] * sv.x + scsh2[64 + c0 + 0]);
    o.y = softplusf_(hv.y + scsh2[c0 + 1] * sv.y + scsh2[64 + c0 + 1]);
    o.z = softplusf_(hv.z + scsh2[c0 + 2] * sv.z + scsh2[64 + c0 + 2]);
    o.w = softplusf_(hv.w + scsh2[c0 + 3] * sv.w + scsh2[64 + c0 + 3]);
    *(float4*)&h[i] = o;
}

// ---------------- pooling ----------------
__device__ __forceinline__ int lbound(const int* a, int n, int v) {
    int lo = 0, hi = n;
    while (lo < hi) { int mid = (lo + hi) >> 1; if (a[mid] < v) lo = mid + 1; else hi = mid; }
    return lo;
}

__global__ __launch_bounds__(256) void k_pool(const float* __restrict__ h,
        const int* __restrict__ cidx, float* __restrict__ feats) {
    __shared__ float red[4][68];
    __shared__ int bounds[2];
    int c = blockIdx.x, tid = threadIdx.x;
    if (tid == 0) {
        bounds[0] = lbound(cidx, NN, c);
        bounds[1] = lbound(cidx, NN, c + 1);
    }
    __syncthreads();
    int lo = bounds[0], hi = bounds[1];
    int d = tid & 63, g = tid >> 6;
    float acc = 0;
    for (int n = lo + g; n < hi; n += 4) acc += h[(size_t)n * 64 + d];
    red[g][d] = acc;
    __syncthreads();
    if (tid < 64) {
        float t = red[0][tid] + red[1][tid] + red[2][tid] + red[3][tid];
        int cnt = hi - lo;
        feats[(size_t)c * 65 + tid] = t / (float)(cnt > 0 ? cnt : 1);
    }
}

// ---------------- head ----------------
__global__ __launch_bounds__(128) void k_head1(float* __restrict__ feats, const float* __restrict__ fap,
        const float* __restrict__ g, const float* __restrict__ b, float* __restrict__ featsp) {
    int tid = threadIdx.x;
    if (tid < CC) feats[(size_t)tid * 65 + 64] = fap[tid];
    __syncthreads();
    if (tid < 65) {
        float s = 0;
        for (int r = 0; r < CC; ++r) s += feats[r * 65 + tid];
        float m = s / (float)CC;
        float v = 0;
        for (int r = 0; r < CC; ++r) { float d = feats[r * 65 + tid] - m; v += d * d; }
        v /= (float)CC;
        float sc = g[tid] * rsqrtf(v + EPSBN);
        float sh = b[tid] - m * sc;
        for (int r = 0; r < CC; ++r)
            featsp[r * 65 + tid] = softplusf_(sc * feats[r * 65 + tid] + sh);
    }
}

__global__ __launch_bounds__(128) void k_head2(const float* __restrict__ featsp,
        const float* __restrict__ fc2w, const float* __restrict__ fc2b,
        const float* __restrict__ fc3w, const float* __restrict__ fc3b,
        float* __restrict__ out) {
    __shared__ float fr[65];
    __shared__ float red[128];
    int r = blockIdx.x, tid = threadIdx.x;
    if (tid < 65) fr[tid] = featsp[(size_t)r * 65 + tid];
    __syncthreads();
    float acc = fc2b[tid];
    for (int k = 0; k < 65; ++k) acc += fr[k] * fc2w[k * 128 + tid];
    red[tid] = softplusf_(acc) * fc3w[tid];
    __syncthreads();
    for (int st = 64; st > 0; st >>= 1) {
        if (tid < st) red[tid] += red[tid + st];
        __syncthreads();
    }
    if (tid == 0) out[r] = red[0] + fc3b[0];
}

extern "C" void kernel_launch(void* const* d_in, const int* in_sizes, int n_in,
                              void* d_out, int out_size, void* d_ws, size_t ws_size,
                              hipStream_t stream) {
    const float* site  = (const float*)d_in[0];
    const float* bondf = (const float*)d_in[1];
    const float* fap   = (const float*)d_in[2];
    const float* fc1w  = (const float*)d_in[3];
    const float* fc1b  = (const float*)d_in[4];
    const float* convw = (const float*)d_in[5];
    const float* convb = (const float*)d_in[6];
    const float* bn1g  = (const float*)d_in[7];
    const float* bn1b  = (const float*)d_in[8];
    const float* bn2g  = (const float*)d_in[9];
    const float* bn2b  = (const float*)d_in[10];
    const float* topg  = (const float*)d_in[11];
    const float* topb  = (const float*)d_in[12];
    const float* fc2w  = (const float*)d_in[13];
    const float* fc2b  = (const float*)d_in[14];
    const float* fc3w  = (const float*)d_in[15];
    const float* fc3b  = (const float*)d_in[16];
    const int*   bidx  = (const int*)d_in[17];
    const int*   cidx  = (const int*)d_in[18];
    float* out = (float*)d_out;

    char* w = (char*)d_ws;
    constexpr size_t SZ_H  = (size_t)NN * 64 * 4;
    constexpr size_t SZ_HP = (size_t)NN * 128 * 4;
    constexpr size_t OFF_H  = 0;
    constexpr size_t OFF_HI = OFF_H + SZ_H;
    constexpr size_t OFF_HJ = OFF_HI + SZ_HP;
    constexpr size_t OFF_S  = OFF_HJ + SZ_HP;
    constexpr size_t OFF_SCSH1 = OFF_S + SZ_H;
    constexpr size_t OFF_SCSH2 = OFF_SCSH1 + 1024;
    constexpr size_t OFF_P1 = OFF_SCSH2 + 512;
    constexpr size_t OFF_P2 = OFF_P1 + (size_t)G_BOND * 256 * 4;
    constexpr size_t OFF_PA = OFF_P2 + (size_t)G_APPLY * 128 * 4;
    constexpr size_t OFF_PB = OFF_PA + (size_t)RED_B * 256 * 4;
    constexpr size_t OFF_FE = OFF_PB + (size_t)RED_B * 128 * 4;
    constexpr size_t OFF_FP = OFF_FE + 128 * 65 * 4;
    constexpr size_t OFF_T  = ((OFF_FP + 128 * 65 * 4) + 255) & ~(size_t)255;
    constexpr size_t OFF_BFQ = OFF_T + (size_t)NBOND * 128 * 2;
    constexpr size_t NEED_BFQ = OFF_BFQ + (size_t)NBOND * 64 * 2;

    float* h      = (float*)(w + OFF_H);
    float* hi     = (float*)(w + OFF_HI);
    float* hj     = (float*)(w + OFF_HJ);
    float* sbuf   = (float*)(w + OFF_S);
    float* scsh1  = (float*)(w + OFF_SCSH1);
    float* scsh2  = (float*)(w + OFF_SCSH2);
    float* part1  = (float*)(w + OFF_P1);
    float* part2  = (float*)(w + OFF_P2);
    float* partA  = (float*)(w + OFF_PA);
    float* partB  = (float*)(w + OFF_PB);
    float* feats  = (float*)(w + OFF_FE);
    float* featsp = (float*)(w + OFF_FP);
    unsigned short* tbuf = (unsigned short*)(w + OFF_T);
    unsigned short* bfq  = (unsigned short*)(w + OFF_BFQ);

    const bool useq = (ws_size >= NEED_BFQ);

    if (useq) k_cvt<<<NBOND * 64 / (256 * 8), 256, 0, stream>>>(bondf, bfq);
    k_fc1<<<2500, 256, 0, stream>>>(site, fc1w, fc1b, h);
    for (int l = 0; l < LL; ++l) {
        const float* cw = convw + (size_t)l * 192 * 128;
        const float* cb = convb + l * 128;
        k_proj<<<1250, 256, 0, stream>>>(h, cw, cb, hi, hj);
        if (useq)
            k_bond<true><<<G_BOND, 256, 0, stream>>>(bondf, bfq, cw + 128 * 128, hi, hj, bidx, tbuf, part1);
        else
            k_bond<false><<<G_BOND, 256, 0, stream>>>(bondf, bfq, cw + 128 * 128, hi, hj, bidx, tbuf, part1);
        k_red1<<<RED_B, 256, 0, stream>>>(part1, partA);
        k_fin1<<<1, 256, 0, stream>>>(partA, bn1g + l * 128, bn1b + l * 128, scsh1);
        k_apply<<<G_APPLY, 256, 0, stream>>>(tbuf, scsh1, sbuf, part2);
        k_red2<<<RED_B, 128, 0, stream>>>(part2, partB);
        k_fin2<<<1, 128, 0, stream>>>(partB, bn2g + l * 64, bn2b + l * 64, scsh2);
        k_upd<<<2500, 256, 0, stream>>>(h, sbuf, scsh2);
    }
    k_pool<<<128, 256, 0, stream>>>(h, cidx, feats);
    k_head1<<<1, 128, 0, stream>>>(feats, fap, topg, topb, featsp);
    k_head2<<<128, 128, 0, stream>>>(featsp, fc2w, fc2b, fc3w, fc3b, out);
}